// Round 1
// baseline (250.145 us; speedup 1.0000x reference)
//
#include <hip/hip_runtime.h>

typedef __attribute__((ext_vector_type(8))) short short8;
typedef __attribute__((ext_vector_type(8))) unsigned short ushort8;
typedef __attribute__((ext_vector_type(4))) float f32x4;

__device__ __forceinline__ float bf2f(unsigned short u) {
  union { unsigned int u; float f; } c; c.u = ((unsigned int)u) << 16; return c.f;
}
__device__ __forceinline__ unsigned short f2bf(float f) {
  union { float f; unsigned int u; } c; c.f = f;
  unsigned int x = c.u;
  return (unsigned short)((x + 0x7FFFu + ((x >> 16) & 1u)) >> 16);
}

#define GLD_LDS16(g, l)                                                        \
  __builtin_amdgcn_global_load_lds(                                            \
      (const __attribute__((address_space(1))) void*)(g),                      \
      (__attribute__((address_space(3))) void*)(l), 16, 0, 0)

__device__ __forceinline__ void bar() {
  asm volatile("" ::: "memory");
  __builtin_amdgcn_s_barrier();
  asm volatile("" ::: "memory");
}

// --------------------------------------------------- fused prep:
// [0,4096): cast X fp32 -> bf16
// [4096,4864): transpose+cast W[1024][3072] -> Wt[3072][1024] bf16
// 4864: zero Lrow
__global__ __launch_bounds__(256) void prep_kernel(
    const float* __restrict__ X, unsigned short* __restrict__ Xb,
    const float* __restrict__ W, unsigned short* __restrict__ Wt,
    float* __restrict__ Lrow) {
  const int t = threadIdx.x;
  if (blockIdx.x < 4096) {
    long i = ((long)blockIdx.x * 256 + t) * 8;
    float4 a = *(const float4*)(X + i);
    float4 b = *(const float4*)(X + i + 4);
    ushort8 o;
    o[0] = f2bf(a.x); o[1] = f2bf(a.y); o[2] = f2bf(a.z); o[3] = f2bf(a.w);
    o[4] = f2bf(b.x); o[5] = f2bf(b.y); o[6] = f2bf(b.z); o[7] = f2bf(b.w);
    *(ushort8*)(Xb + i) = o;
  } else if (blockIdx.x < 4864) {
    const int bid = blockIdx.x - 4096;          // 768 blocks = 48 x 16
    const int f0 = (bid % 48) * 64;
    const int e0 = (bid / 48) * 64;
    __shared__ unsigned short tile[64][65];
    const int cg = (t & 15) * 4;
    const int r = t >> 4;
#pragma unroll
    for (int i = 0; i < 4; ++i) {
      int e = r + i * 16;
      float4 v = *(const float4*)(W + (long)(e0 + e) * 3072 + f0 + cg);
      tile[e][cg + 0] = f2bf(v.x);
      tile[e][cg + 1] = f2bf(v.y);
      tile[e][cg + 2] = f2bf(v.z);
      tile[e][cg + 3] = f2bf(v.w);
    }
    __syncthreads();
#pragma unroll
    for (int i = 0; i < 4; ++i) {
      int f = (t >> 4) + i * 16;
      int e = (t & 15) * 4;
      ushort4 o;
      o.x = tile[e + 0][f];
      o.y = tile[e + 1][f];
      o.z = tile[e + 2][f];
      o.w = tile[e + 3][f];
      *(ushort4*)(Wt + (long)(f0 + f) * 1024 + e0 + e) = o;
    }
  } else {
    float4 z = {0.f, 0.f, 0.f, 0.f};
#pragma unroll
    for (int j = 0; j < 8; ++j) *(float4*)(Lrow + (j * 256 + t) * 4) = z;
  }
}

// ================================================================
// 256x256 8-phase GEMM body (C = A * B^T), BK=64, 512 threads, 8 waves.
// LDS (128 KiB): per buffer (2): A-k0[256][32] | A-k1[256][32] | B-k0 | B-k1
//   (K-half sub-layout: row stride 64 B -> fragment ds_read_b128 is naturally
//    bank-conflict-free; global_load_lds dest stays linear.)
// Per K-tile: 4 phases x 16 MFMA; ds_reads 8/4/8/4; stage 1 half (2 GLD)/phase:
//   P1: stage (T+1).A-k1   P2: stage (T+1).B-k1
//   P3: stage (T+2).B-k0   P4: stage (T+2).A-k0    then s_waitcnt vmcnt(4)
// Region deaths (last ds_read): B-k0@P1, A-k0@P2, B-k1@P3, A-k1@P4 — every
// stage targets a region dead >=1 barrier earlier; vmcnt(4) at tile end leaves
// exactly P3+P4's 4 loads in flight, so tile T+1 is fully landed.
// MODE 0 (qkv): bx<8 -> bf16 to QK; bx>=8 -> LDS-transpose -> Vt.
// MODE 1 (score): bf16 exp(acc*alpha) + row-sum atomicAdd into Lrow.
// ================================================================
template <int MODE>
__device__ __forceinline__ void gemm256_body(
    const unsigned short* __restrict__ A, const unsigned short* __restrict__ B,
    void* __restrict__ Cv, int K, int lda, int ldb, int ldc,
    long sA, long sB, long sC, float alpha, float* __restrict__ Lrow,
    unsigned short* __restrict__ Vt) {
  __shared__ __align__(16) unsigned short smem[65536];  // 128 KiB

  const int t = threadIdx.x;
  const int lane = t & 63;
  const int wave = t >> 6;        // 0..7
  const int quad = lane >> 4;     // 0..3
  const int mrow = lane & 15;     // 0..15
  const int wm = wave >> 2;       // 0..1  (M half)
  const int wn = wave & 3;        // 0..3  (N quarter)

  const int bx = blockIdx.x, by = blockIdx.y, b = blockIdx.z;
  const int rowA0 = by * 256;
  const int rowB0 = bx * 256;
  const unsigned short* Ab = A + (long)b * sA;
  const unsigned short* Bb = B + (long)b * sB;

  // staging lane split: 16 rows x 32 cols per GLD round
  const int srow = lane >> 2;          // 0..15
  const int schunk = (lane & 3) * 8;   // 0/8/16/24 elems

  f32x4 acc[8][4];
#pragma unroll
  for (int i = 0; i < 8; ++i)
#pragma unroll
    for (int j = 0; j < 4; ++j) {
      f32x4 z = {0.f, 0.f, 0.f, 0.f};
      acc[i][j] = z;
    }

  const int NT = K >> 6;  // assumed >= 3

  // stage one K-half (256 rows x 32 k) of A or B for k-offset kt into region
  auto stg = [&](const unsigned short* gb, int ld, int r0, int kt, int kh,
                 int roff) {
#pragma unroll
    for (int j = 0; j < 2; ++j)
      GLD_LDS16(gb + (long)(r0 + j * 128 + wave * 16 + srow) * ld + kt +
                    kh * 32 + schunk,
                smem + roff + (j * 128 + wave * 16) * 32);
  };

  // prologue: T0 fully + T1.{B-k0, A-k0}  (issue order matters for vmcnt(4))
  stg(Ab, lda, rowA0, 0, 0, 0);
  stg(Bb, ldb, rowB0, 0, 0, 16384);
  stg(Ab, lda, rowA0, 0, 1, 8192);
  stg(Bb, ldb, rowB0, 0, 1, 24576);
  stg(Bb, ldb, rowB0, 64, 0, 32768 + 16384);
  stg(Ab, lda, rowA0, 64, 0, 32768);
  asm volatile("s_waitcnt vmcnt(4)" ::: "memory");
  bar();

  const int rA_base = wm * 128 + mrow;
  const int rB_base = wn * 64 + mrow;
  const int qoff = quad * 8;

  for (int T = 0; T < NT; ++T) {
    const int buf = (T & 1) << 15;   // 0 or 32768
    const int nbuf = buf ^ 32768;
    const unsigned short* A0 = smem + buf;
    const unsigned short* A1 = smem + buf + 8192;
    const unsigned short* B0 = smem + buf + 16384;
    const unsigned short* B1 = smem + buf + 24576;
    const int ktn = (T + 1) << 6;
    const int ktn2 = (T + 2) << 6;
    short8 af[4], bf[4];

    // ---------------- P1: ks=0, m-half 0 (8 ds_reads) ----------------
#pragma unroll
    for (int i = 0; i < 4; ++i)
      af[i] = *(const short8*)(A0 + (rA_base + i * 16) * 32 + qoff);
#pragma unroll
    for (int j = 0; j < 4; ++j)
      bf[j] = *(const short8*)(B0 + (rB_base + j * 16) * 32 + qoff);
    if (T + 1 < NT) stg(Ab, lda, rowA0, ktn, 1, nbuf + 8192);
    bar();
    __builtin_amdgcn_sched_barrier(0);
    __builtin_amdgcn_s_setprio(1);
#pragma unroll
    for (int i = 0; i < 4; ++i)
#pragma unroll
      for (int j = 0; j < 4; ++j)
        acc[i][j] = __builtin_amdgcn_mfma_f32_16x16x32_bf16(af[i], bf[j],
                                                            acc[i][j], 0, 0, 0);
    __builtin_amdgcn_s_setprio(0);
    __builtin_amdgcn_sched_barrier(0);
    bar();

    // ---------------- P2: ks=0, m-half 1 (4 ds_reads) ----------------
#pragma unroll
    for (int i = 0; i < 4; ++i)
      af[i] = *(const short8*)(A0 + (rA_base + 64 + i * 16) * 32 + qoff);
    if (T + 1 < NT) stg(Bb, ldb, rowB0, ktn, 1, nbuf + 24576);
    bar();
    __builtin_amdgcn_sched_barrier(0);
    __builtin_amdgcn_s_setprio(1);
#pragma unroll
    for (int i = 0; i < 4; ++i)
#pragma unroll
      for (int j = 0; j < 4; ++j)
        acc[4 + i][j] = __builtin_amdgcn_mfma_f32_16x16x32_bf16(
            af[i], bf[j], acc[4 + i][j], 0, 0, 0);
    __builtin_amdgcn_s_setprio(0);
    __builtin_amdgcn_sched_barrier(0);
    bar();

    // ---------------- P3: ks=1, m-half 0 (8 ds_reads) ----------------
#pragma unroll
    for (int i = 0; i < 4; ++i)
      af[i] = *(const short8*)(A1 + (rA_base + i * 16) * 32 + qoff);
#pragma unroll
    for (int j = 0; j < 4; ++j)
      bf[j] = *(const short8*)(B1 + (rB_base + j * 16) * 32 + qoff);
    if (T + 2 < NT) stg(Bb, ldb, rowB0, ktn2, 0, buf + 16384);
    bar();
    __builtin_amdgcn_sched_barrier(0);
    __builtin_amdgcn_s_setprio(1);
#pragma unroll
    for (int i = 0; i < 4; ++i)
#pragma unroll
      for (int j = 0; j < 4; ++j)
        acc[i][j] = __builtin_amdgcn_mfma_f32_16x16x32_bf16(af[i], bf[j],
                                                            acc[i][j], 0, 0, 0);
    __builtin_amdgcn_s_setprio(0);
    __builtin_amdgcn_sched_barrier(0);
    bar();

    // ---------------- P4: ks=1, m-half 1 (4 ds_reads) ----------------
#pragma unroll
    for (int i = 0; i < 4; ++i)
      af[i] = *(const short8*)(A1 + (rA_base + 64 + i * 16) * 32 + qoff);
    if (T + 2 < NT) stg(Ab, lda, rowA0, ktn2, 0, buf);
    bar();
    __builtin_amdgcn_sched_barrier(0);
    __builtin_amdgcn_s_setprio(1);
#pragma unroll
    for (int i = 0; i < 4; ++i)
#pragma unroll
      for (int j = 0; j < 4; ++j)
        acc[4 + i][j] = __builtin_amdgcn_mfma_f32_16x16x32_bf16(
            af[i], bf[j], acc[4 + i][j], 0, 0, 0);
    __builtin_amdgcn_s_setprio(0);
    __builtin_amdgcn_sched_barrier(0);
    if (T + 2 < NT) {
      asm volatile("s_waitcnt vmcnt(4)" ::: "memory");
    } else if (T + 1 < NT) {
      asm volatile("s_waitcnt vmcnt(0)" ::: "memory");
    }
    bar();
  }

  // -------------------- epilogue --------------------
  const long cb = (long)b * sC;

  if constexpr (MODE == 0) {
    if (bx < 8) {
      unsigned short* C = (unsigned short*)Cv;
#pragma unroll
      for (int m = 0; m < 8; ++m) {
        int row = rowA0 + wm * 128 + m * 16 + quad * 4;
#pragma unroll
        for (int j = 0; j < 4; ++j) {
          int col = rowB0 + wn * 64 + j * 16 + mrow;
#pragma unroll
          for (int r = 0; r < 4; ++r)
            C[(long)(row + r) * ldc + col] = f2bf(acc[m][j][r]);
        }
      }
    } else {
      // V: transpose via LDS (smem reused as [e 256][s 256] bf16, 128 KiB)
      // swz bits 3-6 only -> 4-aligned ushort4 writes / 8-aligned ushort8 reads
#pragma unroll
      for (int m = 0; m < 8; ++m) {
        int s4 = wm * 128 + m * 16 + quad * 4;
#pragma unroll
        for (int j = 0; j < 4; ++j) {
          int e = wn * 64 + j * 16 + mrow;
          int swz = ((e & 7) << 4) ^ (((e >> 3) & 3) << 3);
          ushort4 pk;
          pk.x = f2bf(acc[m][j][0]);
          pk.y = f2bf(acc[m][j][1]);
          pk.z = f2bf(acc[m][j][2]);
          pk.w = f2bf(acc[m][j][3]);
          *(ushort4*)(smem + e * 256 + (s4 ^ swz)) = pk;
        }
      }
      __syncthreads();
      const int batch = by >> 3;
      const int s_base = (by & 7) * 256;
      const int e_base = (bx - 8) * 256;
      unsigned short* VtB = Vt + (long)batch * 1024 * 2048;
      const int er = t >> 5;          // 0..15
      const int s = (t & 31) * 8;     // 0..248
#pragma unroll
      for (int rnd = 0; rnd < 16; ++rnd) {
        int e = rnd * 16 + er;
        int swz = ((e & 7) << 4) ^ (((e >> 3) & 3) << 3);
        ushort8 v = *(const ushort8*)(smem + e * 256 + (s ^ swz));
        *(ushort8*)(VtB + (long)(e_base + e) * 2048 + s_base + s) = v;
      }
    }
  } else {
    // MODE 1: E = exp(acc*alpha) -> bf16; row sums -> Lrow
    unsigned short* C = (unsigned short*)Cv;
    float p[8][4];
#pragma unroll
    for (int m = 0; m < 8; ++m)
#pragma unroll
      for (int r = 0; r < 4; ++r) p[m][r] = 0.f;
#pragma unroll
    for (int m = 0; m < 8; ++m) {
      int row = rowA0 + wm * 128 + m * 16 + quad * 4;
#pragma unroll
      for (int j = 0; j < 4; ++j) {
        int col = rowB0 + wn * 64 + j * 16 + mrow;
#pragma unroll
        for (int r = 0; r < 4; ++r) {
          float e = __expf(acc[m][j][r] * alpha);
          C[cb + (long)(row + r) * ldc + col] = f2bf(e);
          p[m][r] += e;
        }
      }
    }
#pragma unroll
    for (int off = 1; off < 16; off <<= 1)
#pragma unroll
      for (int m = 0; m < 8; ++m)
#pragma unroll
        for (int r = 0; r < 4; ++r)
          p[m][r] += __shfl_xor(p[m][r], off, 64);
    if (mrow == 0) {
#pragma unroll
      for (int m = 0; m < 8; ++m) {
        int row = rowA0 + wm * 128 + m * 16 + quad * 4;
#pragma unroll
        for (int r = 0; r < 4; ++r)
          atomicAdd(&Lrow[b * 2048 + row + r], p[m][r]);
      }
    }
  }
}

// ---------------------------------------------------------------- m97 body,
// kept for the out GEMM (MODE 2 only: fp32 store of acc/Lrow[row]).
// (256-block 256^2 grid would idle half the CUs there; m97 at 512 blocks x
//  2/CU is equivalent — see R0 analysis.)
template <int MODE>
__device__ __forceinline__ void gemm_body(
    const unsigned short* __restrict__ A, const unsigned short* __restrict__ B,
    void* __restrict__ Cv, int K, int lda, int ldb, int ldc,
    long sA, long sB, long sC, float alpha, float* __restrict__ Lrow,
    unsigned short* __restrict__ Vt) {
  constexpr int BM = 128, BN = 128, BK = 64;
  __shared__ __align__(16) unsigned short smem[BM * BK + BN * BK];  // 32 KB
  unsigned short* As = smem;
  unsigned short* Bs = smem + BM * BK;

  const int t = threadIdx.x;
  const int lane = t & 63;
  const int wave = t >> 6;
  const int quad = lane >> 4;
  const int mrow = lane & 15;
  const int wm = wave >> 1, wn = wave & 1;

  const int bx = blockIdx.x, by = blockIdx.y;
  const int rowA0 = by * BM;
  const int rowB0 = bx * BN;
  const int b = blockIdx.z;
  const unsigned short* Ab = A + (long)b * sA;
  const unsigned short* Bb = B + (long)b * sB;

  f32x4 acc[4][4];
#pragma unroll
  for (int i = 0; i < 4; ++i)
#pragma unroll
    for (int j = 0; j < 4; ++j) {
      f32x4 z = {0.f, 0.f, 0.f, 0.f};
      acc[i][j] = z;
    }

  const int rbase = wave * 32 + (lane >> 3);
  const int c2 = lane & 7;

  for (int kt = 0; kt < K; kt += BK) {
#pragma unroll
    for (int j = 0; j < 4; ++j) {
      int r = rbase + j * 8;
      int c = c2 ^ (r & 7);
      GLD_LDS16(Ab + (long)(rowA0 + r) * lda + kt + c * 8, As + (wave * 4 + j) * 512);
      GLD_LDS16(Bb + (long)(rowB0 + r) * ldb + kt + c * 8, Bs + (wave * 4 + j) * 512);
    }
    __syncthreads();
#pragma unroll
    for (int ks = 0; ks < 2; ++ks) {
      short8 af[4], bfr[4];
#pragma unroll
      for (int i = 0; i < 4; ++i) {
        int rA = wm * 64 + i * 16 + mrow;
        int cc = ks * 4 + quad;
        af[i] = *(const short8*)(As + (rA * 8 + (cc ^ (rA & 7))) * 8);
        int rB = wn * 64 + i * 16 + mrow;
        bfr[i] = *(const short8*)(Bs + (rB * 8 + (cc ^ (rB & 7))) * 8);
      }
#pragma unroll
      for (int mt = 0; mt < 4; ++mt)
#pragma unroll
        for (int nt = 0; nt < 4; ++nt)
          acc[mt][nt] = __builtin_amdgcn_mfma_f32_16x16x32_bf16(
              af[mt], bfr[nt], acc[mt][nt], 0, 0, 0);
    }
    __syncthreads();
  }

  const int m_base = rowA0 + wm * 64;
  const int n_base = rowB0 + wn * 64;
  const long cb = (long)b * sC;

  // MODE 2 only instantiated: fp32 out, scaled by 1/Lrow[row]
#pragma unroll
  for (int mt = 0; mt < 4; ++mt)
#pragma unroll
    for (int i = 0; i < 4; ++i) {
      int row = m_base + mt * 16 + quad * 4 + i;
      float inv = 1.0f / Lrow[b * 2048 + row];
#pragma unroll
      for (int nt = 0; nt < 4; ++nt) {
        int col = n_base + nt * 16 + mrow;
        ((float*)Cv)[cb + (long)row * ldc + col] = acc[mt][nt][i] * inv;
      }
    }
}

// distinct names so rocprof separates the three GEMMs
__global__ __launch_bounds__(512, 2) void qkv_gemm_kernel(
    const unsigned short* __restrict__ A, const unsigned short* __restrict__ B,
    void* __restrict__ Cv, int K, int lda, int ldb, int ldc,
    long sA, long sB, long sC, float alpha, float* __restrict__ Lrow,
    unsigned short* __restrict__ Vt) {
  gemm256_body<0>(A, B, Cv, K, lda, ldb, ldc, sA, sB, sC, alpha, Lrow, Vt);
}
__global__ __launch_bounds__(512, 2) void score_gemm_kernel(
    const unsigned short* __restrict__ A, const unsigned short* __restrict__ B,
    void* __restrict__ Cv, int K, int lda, int ldb, int ldc,
    long sA, long sB, long sC, float alpha, float* __restrict__ Lrow,
    unsigned short* __restrict__ Vt) {
  gemm256_body<1>(A, B, Cv, K, lda, ldb, ldc, sA, sB, sC, alpha, Lrow, Vt);
}
__global__ __launch_bounds__(256, 2) void out_gemm_kernel(
    const unsigned short* __restrict__ A, const unsigned short* __restrict__ B,
    void* __restrict__ Cv, int K, int lda, int ldb, int ldc,
    long sA, long sB, long sC, float alpha, float* __restrict__ Lrow,
    unsigned short* __restrict__ Vt) {
  gemm_body<2>(A, B, Cv, K, lda, ldb, ldc, sA, sB, sC, alpha, Lrow, Vt);
}

// ---------------------------------------------------------------- launch
extern "C" void kernel_launch(void* const* d_in, const int* in_sizes, int n_in,
                              void* d_out, int out_size, void* d_ws, size_t ws_size,
                              hipStream_t stream) {
  const float* X = (const float*)d_in[0];  // [4,2048,1024] fp32
  const float* W = (const float*)d_in[1];  // [1024,3072] fp32
  float* out = (float*)d_out;              // [4,2048,1024] fp32

  char* ws = (char*)d_ws;
  unsigned short* Xb  = (unsigned short*)(ws);                 // 8192x1024 bf16   (16 MiB)
  unsigned short* Wtb = (unsigned short*)(ws + 16777216);      // 3072x1024 bf16   ( 6 MiB)
  unsigned short* QK  = (unsigned short*)(ws + 23068672);      // 8192x2048 bf16   (32 MiB)
  unsigned short* Vt  = (unsigned short*)(ws + 56623104);      // 4x1024x2048 bf16 (16 MiB)
  unsigned short* Sb  = (unsigned short*)(ws + 73400320);      // 4x2048x2048 bf16 (32 MiB)
  float* Lrow         = (float*)(ws + 106954752);              // 4x2048 fp32      (32 KiB)

  // 1. prep: cast X, transpose W, zero Lrow
  prep_kernel<<<4865, 256, 0, stream>>>(X, Xb, W, Wtb, Lrow);

  // 2. [Q|K] = Xb @ Wtb^T  (bx<8 -> QK, ldc=2048); V -> Vt transposed (bx>=8)
  qkv_gemm_kernel<<<dim3(12, 32, 1), 512, 0, stream>>>(
      Xb, Wtb, QK, 1024, 1024, 1024, 2048, 0L, 0L, 0L, 1.0f, nullptr, Vt);

  // 3. E = exp(Q @ K^T / 32) per batch [2048 x 2048], K=1024; row sums -> Lrow
  score_gemm_kernel<<<dim3(8, 8, 4), 512, 0, stream>>>(
      QK, QK + 1024, Sb, 1024, 2048, 2048, 2048,
      (long)2048 * 2048, (long)2048 * 2048, (long)2048 * 2048, 0.03125f, Lrow, nullptr);

  // 4. O = (E @ Vt^T) / L  per batch  [2048 x 1024], K=2048 -> fp32 out
  out_gemm_kernel<<<dim3(8, 16, 4), 256, 0, stream>>>(
      Sb, Vt, out, 2048, 2048, 2048, 1024,
      (long)2048 * 2048, (long)1024 * 2048, (long)2048 * 1024, 1.0f, Lrow, nullptr);
}

// Round 2
// 239.080 us; speedup vs baseline: 1.0463x; 1.0463x over previous
//
#include <hip/hip_runtime.h>

typedef __attribute__((ext_vector_type(8))) short short8;
typedef __attribute__((ext_vector_type(8))) unsigned short ushort8;
typedef __attribute__((ext_vector_type(4))) float f32x4;

__device__ __forceinline__ float bf2f(unsigned short u) {
  union { unsigned int u; float f; } c; c.u = ((unsigned int)u) << 16; return c.f;
}
__device__ __forceinline__ unsigned short f2bf(float f) {
  union { float f; unsigned int u; } c; c.f = f;
  unsigned int x = c.u;
  return (unsigned short)((x + 0x7FFFu + ((x >> 16) & 1u)) >> 16);
}

#define GLD_LDS16(g, l)                                                        \
  __builtin_amdgcn_global_load_lds(                                            \
      (const __attribute__((address_space(1))) void*)(g),                      \
      (__attribute__((address_space(3))) void*)(l), 16, 0, 0)

__device__ __forceinline__ void bar() {
  asm volatile("" ::: "memory");
  __builtin_amdgcn_s_barrier();
  asm volatile("" ::: "memory");
}

// --------------------------------------------------- fused prep:
// [0,4096): cast X fp32 -> bf16
// [4096,4864): transpose+cast W[1024][3072] -> Wt[3072][1024] bf16
// 4864: zero Lrow
__global__ __launch_bounds__(256) void prep_kernel(
    const float* __restrict__ X, unsigned short* __restrict__ Xb,
    const float* __restrict__ W, unsigned short* __restrict__ Wt,
    float* __restrict__ Lrow) {
  const int t = threadIdx.x;
  if (blockIdx.x < 4096) {
    long i = ((long)blockIdx.x * 256 + t) * 8;
    float4 a = *(const float4*)(X + i);
    float4 b = *(const float4*)(X + i + 4);
    ushort8 o;
    o[0] = f2bf(a.x); o[1] = f2bf(a.y); o[2] = f2bf(a.z); o[3] = f2bf(a.w);
    o[4] = f2bf(b.x); o[5] = f2bf(b.y); o[6] = f2bf(b.z); o[7] = f2bf(b.w);
    *(ushort8*)(Xb + i) = o;
  } else if (blockIdx.x < 4864) {
    const int bid = blockIdx.x - 4096;          // 768 blocks = 48 x 16
    const int f0 = (bid % 48) * 64;
    const int e0 = (bid / 48) * 64;
    __shared__ unsigned short tile[64][65];
    const int cg = (t & 15) * 4;
    const int r = t >> 4;
#pragma unroll
    for (int i = 0; i < 4; ++i) {
      int e = r + i * 16;
      float4 v = *(const float4*)(W + (long)(e0 + e) * 3072 + f0 + cg);
      tile[e][cg + 0] = f2bf(v.x);
      tile[e][cg + 1] = f2bf(v.y);
      tile[e][cg + 2] = f2bf(v.z);
      tile[e][cg + 3] = f2bf(v.w);
    }
    __syncthreads();
#pragma unroll
    for (int i = 0; i < 4; ++i) {
      int f = (t >> 4) + i * 16;
      int e = (t & 15) * 4;
      ushort4 o;
      o.x = tile[e + 0][f];
      o.y = tile[e + 1][f];
      o.z = tile[e + 2][f];
      o.w = tile[e + 3][f];
      *(ushort4*)(Wt + (long)(f0 + f) * 1024 + e0 + e) = o;
    }
  } else {
    float4 z = {0.f, 0.f, 0.f, 0.f};
#pragma unroll
    for (int j = 0; j < 8; ++j) *(float4*)(Lrow + (j * 256 + t) * 4) = z;
  }
}

// ================================================================
// 256x256 8-phase GEMM body (C = A * B^T), BK=64, 512 threads, 8 waves.
// LDS (128 KiB), per buffer (2): A[256 rows][64 k] | B[256][64], bf16,
// 128 B rows with m97 XOR-8 slot swizzle: LDS slot s of row r holds global
// k-slot s^(r&7). Staged via linear-dest global_load_lds with pre-swizzled
// per-lane source col ((lane&7)^(lane>>3))*8; frag ds_read_b128 at slot
// cc^(r&7) — measured-conflict-free pattern (m97/m98: ~0 conflicts).
// Staging unit = 8 rows x 128 B = 1 GLD/wave; A unit j covers rows
// j*64+wave*8..+7 (j in {0,2} -> h0 rows, {1,3} -> h1), B unit j same rows.
// Region deaths in tile T: A-h0 & B after P3, A-h1 after P4. Schedule
// (per wave, uniform): P1: A0,A2(T+1)->nbuf; P2: A1,A3(T+1); P3: B2,B3(T+1);
// P4: B0,B1(T+2)->buf; end-of-tile s_waitcnt vmcnt(2) (never 0 mid-loop).
// MODE 0 (qkv): bx<8 -> bf16 to QK; bx>=8 -> LDS-transpose -> Vt.
// MODE 1 (score): bf16 exp(acc*alpha) + row-sum atomicAdd into Lrow.
// ================================================================
template <int MODE>
__device__ __forceinline__ void gemm256_body(
    const unsigned short* __restrict__ A, const unsigned short* __restrict__ B,
    void* __restrict__ Cv, int K, int lda, int ldb, int ldc,
    long sA, long sB, long sC, float alpha, float* __restrict__ Lrow,
    unsigned short* __restrict__ Vt) {
  __shared__ __align__(16) unsigned short smem[65536];  // 128 KiB

  const int t = threadIdx.x;
  const int lane = t & 63;
  const int wave = t >> 6;        // 0..7
  const int quad = lane >> 4;     // 0..3
  const int mrow = lane & 15;     // 0..15
  const int wm = wave >> 2;       // 0..1  (M half)
  const int wn = wave & 3;        // 0..3  (N quarter)

  const int bx = blockIdx.x, by = blockIdx.y, b = blockIdx.z;
  const int rowA0 = by * 256;
  const int rowB0 = bx * 256;
  const unsigned short* Ab = A + (long)b * sA;
  const unsigned short* Bb = B + (long)b * sB;

  // staging: lane l -> row (l>>3), global k-slot (l&7)^(l>>3); dest linear
  const int srow = lane >> 3;                 // 0..7
  const int scol = ((lane & 7) ^ srow) * 8;   // pre-swizzled source col (elems)

  f32x4 acc[8][4];
#pragma unroll
  for (int i = 0; i < 8; ++i)
#pragma unroll
    for (int j = 0; j < 4; ++j) {
      f32x4 z = {0.f, 0.f, 0.f, 0.f};
      acc[i][j] = z;
    }

  const int NT = K >> 6;  // 16 here (>= 3 assumed)

  // stage unit j (8 rows x full 64 k) for k-offset kt into buffer elem-off boff
  auto stg = [&](const unsigned short* gb, int ld, int r0, int kt, int j,
                 int boff) {
    int rl = j * 64 + wave * 8;
    GLD_LDS16(gb + (long)(r0 + rl + srow) * ld + kt + scol,
              smem + boff + rl * 64);
  };

  // prologue: T0 fully into buf0, then T1.{B0,B1} into buf1
  {
#pragma unroll
    for (int j = 0; j < 4; ++j) stg(Ab, lda, rowA0, 0, j, 0);
#pragma unroll
    for (int j = 0; j < 4; ++j) stg(Bb, ldb, rowB0, 0, j, 16384);
    if (NT > 1) {
      stg(Bb, ldb, rowB0, 64, 0, 32768 + 16384);
      stg(Bb, ldb, rowB0, 64, 1, 32768 + 16384);
      asm volatile("s_waitcnt vmcnt(2)" ::: "memory");
    } else {
      asm volatile("s_waitcnt vmcnt(0)" ::: "memory");
    }
    bar();
  }

  const int m7 = mrow & 7;
  const int aslot0 = (quad ^ m7) * 8;  // ks=0 read slot (elems); ks=1: ^32

  for (int T = 0; T < NT; ++T) {
    const int boff = (T & 1) << 15;  // 0 / 32768 elems
    const int noff = boff ^ 32768;
    const unsigned short* As = smem + boff;
    const unsigned short* Bs = smem + boff + 16384;
    const int kt1 = (T + 1) << 6;
    const int kt2 = (T + 2) << 6;
    short8 af[4], bf[4];

    // ---------------- P1: ks=0, m-half 0 ----------------
#pragma unroll
    for (int i = 0; i < 4; ++i)
      af[i] = *(const short8*)(As + (wm * 128 + i * 16 + mrow) * 64 + aslot0);
#pragma unroll
    for (int j = 0; j < 4; ++j)
      bf[j] = *(const short8*)(Bs + (wn * 64 + j * 16 + mrow) * 64 + aslot0);
    if (T + 1 < NT) {
      stg(Ab, lda, rowA0, kt1, 0, noff);
      stg(Ab, lda, rowA0, kt1, 2, noff);
    }
    bar();
    __builtin_amdgcn_sched_barrier(0);
    __builtin_amdgcn_s_setprio(1);
#pragma unroll
    for (int i = 0; i < 4; ++i)
#pragma unroll
      for (int j = 0; j < 4; ++j)
        acc[i][j] = __builtin_amdgcn_mfma_f32_16x16x32_bf16(af[i], bf[j],
                                                            acc[i][j], 0, 0, 0);
    __builtin_amdgcn_s_setprio(0);
    __builtin_amdgcn_sched_barrier(0);
    bar();

    // ---------------- P2: ks=0, m-half 1 (bf reused) ----------------
#pragma unroll
    for (int i = 0; i < 4; ++i)
      af[i] =
          *(const short8*)(As + (wm * 128 + 64 + i * 16 + mrow) * 64 + aslot0);
    if (T + 1 < NT) {
      stg(Ab, lda, rowA0, kt1, 1, noff);
      stg(Ab, lda, rowA0, kt1, 3, noff);
    }
    bar();
    __builtin_amdgcn_sched_barrier(0);
    __builtin_amdgcn_s_setprio(1);
#pragma unroll
    for (int i = 0; i < 4; ++i)
#pragma unroll
      for (int j = 0; j < 4; ++j)
        acc[4 + i][j] = __builtin_amdgcn_mfma_f32_16x16x32_bf16(
            af[i], bf[j], acc[4 + i][j], 0, 0, 0);
    __builtin_amdgcn_s_setprio(0);
    __builtin_amdgcn_sched_barrier(0);
    bar();

    // ---------------- P3: ks=1, m-half 0 ----------------
#pragma unroll
    for (int i = 0; i < 4; ++i)
      af[i] = *(const short8*)(As + (wm * 128 + i * 16 + mrow) * 64 +
                               (aslot0 ^ 32));
#pragma unroll
    for (int j = 0; j < 4; ++j)
      bf[j] = *(const short8*)(Bs + (wn * 64 + j * 16 + mrow) * 64 +
                               (aslot0 ^ 32));
    if (T + 1 < NT) {
      stg(Bb, ldb, rowB0, kt1, 2, noff + 16384);
      stg(Bb, ldb, rowB0, kt1, 3, noff + 16384);
    }
    bar();
    __builtin_amdgcn_sched_barrier(0);
    __builtin_amdgcn_s_setprio(1);
#pragma unroll
    for (int i = 0; i < 4; ++i)
#pragma unroll
      for (int j = 0; j < 4; ++j)
        acc[i][j] = __builtin_amdgcn_mfma_f32_16x16x32_bf16(af[i], bf[j],
                                                            acc[i][j], 0, 0, 0);
    __builtin_amdgcn_s_setprio(0);
    __builtin_amdgcn_sched_barrier(0);
    bar();

    // ---------------- P4: ks=1, m-half 1 (bf reused) ----------------
#pragma unroll
    for (int i = 0; i < 4; ++i)
      af[i] = *(const short8*)(As + (wm * 128 + 64 + i * 16 + mrow) * 64 +
                               (aslot0 ^ 32));
    if (T + 2 < NT) {
      stg(Bb, ldb, rowB0, kt2, 0, boff + 16384);
      stg(Bb, ldb, rowB0, kt2, 1, boff + 16384);
    }
    bar();
    __builtin_amdgcn_sched_barrier(0);
    __builtin_amdgcn_s_setprio(1);
#pragma unroll
    for (int i = 0; i < 4; ++i)
#pragma unroll
      for (int j = 0; j < 4; ++j)
        acc[4 + i][j] = __builtin_amdgcn_mfma_f32_16x16x32_bf16(
            af[i], bf[j], acc[4 + i][j], 0, 0, 0);
    __builtin_amdgcn_s_setprio(0);
    __builtin_amdgcn_sched_barrier(0);
    if (T + 2 < NT) {
      asm volatile("s_waitcnt vmcnt(2)" ::: "memory");
    } else {
      asm volatile("s_waitcnt vmcnt(0)" ::: "memory");
    }
    bar();
  }

  // -------------------- epilogue --------------------
  const long cb = (long)b * sC;

  if constexpr (MODE == 0) {
    if (bx < 8) {
      unsigned short* C = (unsigned short*)Cv;
#pragma unroll
      for (int m = 0; m < 8; ++m) {
        int row = rowA0 + wm * 128 + m * 16 + quad * 4;
#pragma unroll
        for (int j = 0; j < 4; ++j) {
          int col = rowB0 + wn * 64 + j * 16 + mrow;
#pragma unroll
          for (int r = 0; r < 4; ++r)
            C[(long)(row + r) * ldc + col] = f2bf(acc[m][j][r]);
        }
      }
    } else {
      // V: transpose via LDS (smem reused as [e 256][s 256] bf16, 128 KiB)
      // swz bits 3-6 only -> 4-aligned ushort4 writes / 8-aligned ushort8 reads
#pragma unroll
      for (int m = 0; m < 8; ++m) {
        int s4 = wm * 128 + m * 16 + quad * 4;
#pragma unroll
        for (int j = 0; j < 4; ++j) {
          int e = wn * 64 + j * 16 + mrow;
          int swz = ((e & 7) << 4) ^ (((e >> 3) & 3) << 3);
          ushort4 pk;
          pk.x = f2bf(acc[m][j][0]);
          pk.y = f2bf(acc[m][j][1]);
          pk.z = f2bf(acc[m][j][2]);
          pk.w = f2bf(acc[m][j][3]);
          *(ushort4*)(smem + e * 256 + (s4 ^ swz)) = pk;
        }
      }
      __syncthreads();
      const int batch = by >> 3;
      const int s_base = (by & 7) * 256;
      const int e_base = (bx - 8) * 256;
      unsigned short* VtB = Vt + (long)batch * 1024 * 2048;
      const int er = t >> 5;          // 0..15
      const int s = (t & 31) * 8;     // 0..248
#pragma unroll
      for (int rnd = 0; rnd < 16; ++rnd) {
        int e = rnd * 16 + er;
        int swz = ((e & 7) << 4) ^ (((e >> 3) & 3) << 3);
        ushort8 v = *(const ushort8*)(smem + e * 256 + (s ^ swz));
        *(ushort8*)(VtB + (long)(e_base + e) * 2048 + s_base + s) = v;
      }
    }
  } else {
    // MODE 1: E = exp(acc*alpha) -> bf16; row sums -> Lrow
    unsigned short* C = (unsigned short*)Cv;
    float p[8][4];
#pragma unroll
    for (int m = 0; m < 8; ++m)
#pragma unroll
      for (int r = 0; r < 4; ++r) p[m][r] = 0.f;
#pragma unroll
    for (int m = 0; m < 8; ++m) {
      int row = rowA0 + wm * 128 + m * 16 + quad * 4;
#pragma unroll
      for (int j = 0; j < 4; ++j) {
        int col = rowB0 + wn * 64 + j * 16 + mrow;
#pragma unroll
        for (int r = 0; r < 4; ++r) {
          float e = __expf(acc[m][j][r] * alpha);
          C[cb + (long)(row + r) * ldc + col] = f2bf(e);
          p[m][r] += e;
        }
      }
    }
#pragma unroll
    for (int off = 1; off < 16; off <<= 1)
#pragma unroll
      for (int m = 0; m < 8; ++m)
#pragma unroll
        for (int r = 0; r < 4; ++r)
          p[m][r] += __shfl_xor(p[m][r], off, 64);
    if (mrow == 0) {
#pragma unroll
      for (int m = 0; m < 8; ++m) {
        int row = rowA0 + wm * 128 + m * 16 + quad * 4;
#pragma unroll
        for (int r = 0; r < 4; ++r)
          atomicAdd(&Lrow[b * 2048 + row + r], p[m][r]);
      }
    }
  }
}

// ---------------------------------------------------------------- m97 body,
// kept for the out GEMM (MODE 2 only: fp32 store of acc/Lrow[row]).
template <int MODE>
__device__ __forceinline__ void gemm_body(
    const unsigned short* __restrict__ A, const unsigned short* __restrict__ B,
    void* __restrict__ Cv, int K, int lda, int ldb, int ldc,
    long sA, long sB, long sC, float alpha, float* __restrict__ Lrow,
    unsigned short* __restrict__ Vt) {
  constexpr int BM = 128, BN = 128, BK = 64;
  __shared__ __align__(16) unsigned short smem[BM * BK + BN * BK];  // 32 KB
  unsigned short* As = smem;
  unsigned short* Bs = smem + BM * BK;

  const int t = threadIdx.x;
  const int lane = t & 63;
  const int wave = t >> 6;
  const int quad = lane >> 4;
  const int mrow = lane & 15;
  const int wm = wave >> 1, wn = wave & 1;

  const int bx = blockIdx.x, by = blockIdx.y;
  const int rowA0 = by * BM;
  const int rowB0 = bx * BN;
  const int b = blockIdx.z;
  const unsigned short* Ab = A + (long)b * sA;
  const unsigned short* Bb = B + (long)b * sB;

  f32x4 acc[4][4];
#pragma unroll
  for (int i = 0; i < 4; ++i)
#pragma unroll
    for (int j = 0; j < 4; ++j) {
      f32x4 z = {0.f, 0.f, 0.f, 0.f};
      acc[i][j] = z;
    }

  const int rbase = wave * 32 + (lane >> 3);
  const int c2 = lane & 7;

  for (int kt = 0; kt < K; kt += BK) {
#pragma unroll
    for (int j = 0; j < 4; ++j) {
      int r = rbase + j * 8;
      int c = c2 ^ (r & 7);
      GLD_LDS16(Ab + (long)(rowA0 + r) * lda + kt + c * 8, As + (wave * 4 + j) * 512);
      GLD_LDS16(Bb + (long)(rowB0 + r) * ldb + kt + c * 8, Bs + (wave * 4 + j) * 512);
    }
    __syncthreads();
#pragma unroll
    for (int ks = 0; ks < 2; ++ks) {
      short8 af[4], bfr[4];
#pragma unroll
      for (int i = 0; i < 4; ++i) {
        int rA = wm * 64 + i * 16 + mrow;
        int cc = ks * 4 + quad;
        af[i] = *(const short8*)(As + (rA * 8 + (cc ^ (rA & 7))) * 8);
        int rB = wn * 64 + i * 16 + mrow;
        bfr[i] = *(const short8*)(Bs + (rB * 8 + (cc ^ (rB & 7))) * 8);
      }
#pragma unroll
      for (int mt = 0; mt < 4; ++mt)
#pragma unroll
        for (int nt = 0; nt < 4; ++nt)
          acc[mt][nt] = __builtin_amdgcn_mfma_f32_16x16x32_bf16(
              af[mt], bfr[nt], acc[mt][nt], 0, 0, 0);
    }
    __syncthreads();
  }

  const int m_base = rowA0 + wm * 64;
  const int n_base = rowB0 + wn * 64;
  const long cb = (long)b * sC;

  // MODE 2 only instantiated: fp32 out, scaled by 1/Lrow[row]
#pragma unroll
  for (int mt = 0; mt < 4; ++mt)
#pragma unroll
    for (int i = 0; i < 4; ++i) {
      int row = m_base + mt * 16 + quad * 4 + i;
      float inv = 1.0f / Lrow[b * 2048 + row];
#pragma unroll
      for (int nt = 0; nt < 4; ++nt) {
        int col = n_base + nt * 16 + mrow;
        ((float*)Cv)[cb + (long)row * ldc + col] = acc[mt][nt][i] * inv;
      }
    }
}

// distinct names so rocprof separates the three GEMMs
__global__ __launch_bounds__(512, 2) void qkv_gemm_kernel(
    const unsigned short* __restrict__ A, const unsigned short* __restrict__ B,
    void* __restrict__ Cv, int K, int lda, int ldb, int ldc,
    long sA, long sB, long sC, float alpha, float* __restrict__ Lrow,
    unsigned short* __restrict__ Vt) {
  gemm256_body<0>(A, B, Cv, K, lda, ldb, ldc, sA, sB, sC, alpha, Lrow, Vt);
}
__global__ __launch_bounds__(512, 2) void score_gemm_kernel(
    const unsigned short* __restrict__ A, const unsigned short* __restrict__ B,
    void* __restrict__ Cv, int K, int lda, int ldb, int ldc,
    long sA, long sB, long sC, float alpha, float* __restrict__ Lrow,
    unsigned short* __restrict__ Vt) {
  gemm256_body<1>(A, B, Cv, K, lda, ldb, ldc, sA, sB, sC, alpha, Lrow, Vt);
}
__global__ __launch_bounds__(256, 2) void out_gemm_kernel(
    const unsigned short* __restrict__ A, const unsigned short* __restrict__ B,
    void* __restrict__ Cv, int K, int lda, int ldb, int ldc,
    long sA, long sB, long sC, float alpha, float* __restrict__ Lrow,
    unsigned short* __restrict__ Vt) {
  gemm_body<2>(A, B, Cv, K, lda, ldb, ldc, sA, sB, sC, alpha, Lrow, Vt);
}

// ---------------------------------------------------------------- launch
extern "C" void kernel_launch(void* const* d_in, const int* in_sizes, int n_in,
                              void* d_out, int out_size, void* d_ws, size_t ws_size,
                              hipStream_t stream) {
  const float* X = (const float*)d_in[0];  // [4,2048,1024] fp32
  const float* W = (const float*)d_in[1];  // [1024,3072] fp32
  float* out = (float*)d_out;              // [4,2048,1024] fp32

  char* ws = (char*)d_ws;
  unsigned short* Xb  = (unsigned short*)(ws);                 // 8192x1024 bf16   (16 MiB)
  unsigned short* Wtb = (unsigned short*)(ws + 16777216);      // 3072x1024 bf16   ( 6 MiB)
  unsigned short* QK  = (unsigned short*)(ws + 23068672);      // 8192x2048 bf16   (32 MiB)
  unsigned short* Vt  = (unsigned short*)(ws + 56623104);      // 4x1024x2048 bf16 (16 MiB)
  unsigned short* Sb  = (unsigned short*)(ws + 73400320);      // 4x2048x2048 bf16 (32 MiB)
  float* Lrow         = (float*)(ws + 106954752);              // 4x2048 fp32      (32 KiB)

  // 1. prep: cast X, transpose W, zero Lrow
  prep_kernel<<<4865, 256, 0, stream>>>(X, Xb, W, Wtb, Lrow);

  // 2. [Q|K] = Xb @ Wtb^T  (bx<8 -> QK, ldc=2048); V -> Vt transposed (bx>=8)
  qkv_gemm_kernel<<<dim3(12, 32, 1), 512, 0, stream>>>(
      Xb, Wtb, QK, 1024, 1024, 1024, 2048, 0L, 0L, 0L, 1.0f, nullptr, Vt);

  // 3. E = exp(Q @ K^T / 32) per batch [2048 x 2048], K=1024; row sums -> Lrow
  score_gemm_kernel<<<dim3(8, 8, 4), 512, 0, stream>>>(
      QK, QK + 1024, Sb, 1024, 2048, 2048, 2048,
      (long)2048 * 2048, (long)2048 * 2048, (long)2048 * 2048, 0.03125f, Lrow, nullptr);

  // 4. O = (E @ Vt^T) / L  per batch  [2048 x 1024], K=2048 -> fp32 out
  out_gemm_kernel<<<dim3(8, 16, 4), 256, 0, stream>>>(
      Sb, Vt, out, 2048, 2048, 2048, 1024,
      (long)2048 * 2048, (long)1024 * 2048, (long)2048 * 1024, 1.0f, Lrow, nullptr);
}

// Round 3
// 237.574 us; speedup vs baseline: 1.0529x; 1.0063x over previous
//
#include <hip/hip_runtime.h>

typedef __attribute__((ext_vector_type(8))) short short8;
typedef __attribute__((ext_vector_type(8))) unsigned short ushort8;
typedef __attribute__((ext_vector_type(4))) float f32x4;

__device__ __forceinline__ float bf2f(unsigned short u) {
  union { unsigned int u; float f; } c; c.u = ((unsigned int)u) << 16; return c.f;
}
__device__ __forceinline__ unsigned short f2bf(float f) {
  union { float f; unsigned int u; } c; c.f = f;
  unsigned int x = c.u;
  return (unsigned short)((x + 0x7FFFu + ((x >> 16) & 1u)) >> 16);
}

#define GLD_LDS16(g, l)                                                        \
  __builtin_amdgcn_global_load_lds(                                            \
      (const __attribute__((address_space(1))) void*)(g),                      \
      (__attribute__((address_space(3))) void*)(l), 16, 0, 0)

__device__ __forceinline__ void bar() {
  asm volatile("" ::: "memory");
  __builtin_amdgcn_s_barrier();
  asm volatile("" ::: "memory");
}

// XCD-aware bijective block swizzle (requires nwg % 8 == 0, by-fastest
// decomposition so each XCD's contiguous chunk shares B-panels in its L2).
__device__ __forceinline__ void xcd_swizzle(int& bx, int& by, int& b) {
  const int gx = gridDim.x, gy = gridDim.y;
  const int nwg = gx * gy * (int)gridDim.z;
  const int id = blockIdx.x + gx * (blockIdx.y + gy * blockIdx.z);
  const int cpx = nwg >> 3;
  const int sid = (id & 7) * cpx + (id >> 3);
  by = sid % gy;
  const int tmp = sid / gy;
  bx = tmp % gx;
  b = tmp / gx;
}

// --------------------------------------------------- fused prep:
// [0,4096): cast X fp32 -> bf16
// [4096,4864): transpose+cast W[1024][3072] -> Wt[3072][1024] bf16
// 4864: zero Lrow
__global__ __launch_bounds__(256) void prep_kernel(
    const float* __restrict__ X, unsigned short* __restrict__ Xb,
    const float* __restrict__ W, unsigned short* __restrict__ Wt,
    float* __restrict__ Lrow) {
  const int t = threadIdx.x;
  if (blockIdx.x < 4096) {
    long i = ((long)blockIdx.x * 256 + t) * 8;
    float4 a = *(const float4*)(X + i);
    float4 b = *(const float4*)(X + i + 4);
    ushort8 o;
    o[0] = f2bf(a.x); o[1] = f2bf(a.y); o[2] = f2bf(a.z); o[3] = f2bf(a.w);
    o[4] = f2bf(b.x); o[5] = f2bf(b.y); o[6] = f2bf(b.z); o[7] = f2bf(b.w);
    *(ushort8*)(Xb + i) = o;
  } else if (blockIdx.x < 4864) {
    const int bid = blockIdx.x - 4096;          // 768 blocks = 48 x 16
    const int f0 = (bid % 48) * 64;
    const int e0 = (bid / 48) * 64;
    __shared__ unsigned short tile[64][65];
    const int cg = (t & 15) * 4;
    const int r = t >> 4;
#pragma unroll
    for (int i = 0; i < 4; ++i) {
      int e = r + i * 16;
      float4 v = *(const float4*)(W + (long)(e0 + e) * 3072 + f0 + cg);
      tile[e][cg + 0] = f2bf(v.x);
      tile[e][cg + 1] = f2bf(v.y);
      tile[e][cg + 2] = f2bf(v.z);
      tile[e][cg + 3] = f2bf(v.w);
    }
    __syncthreads();
#pragma unroll
    for (int i = 0; i < 4; ++i) {
      int f = (t >> 4) + i * 16;
      int e = (t & 15) * 4;
      ushort4 o;
      o.x = tile[e + 0][f];
      o.y = tile[e + 1][f];
      o.z = tile[e + 2][f];
      o.w = tile[e + 3][f];
      *(ushort4*)(Wt + (long)(f0 + f) * 1024 + e0 + e) = o;
    }
  } else {
    float4 z = {0.f, 0.f, 0.f, 0.f};
#pragma unroll
    for (int j = 0; j < 8; ++j) *(float4*)(Lrow + (j * 256 + t) * 4) = z;
  }
}

// ================================================================
// 256x256 8-phase GEMM body (C = A * B^T), BK=64, 512 threads, 8 waves.
// LDS (128 KiB), per buffer (2): A[256 rows][64 k] | B[256][64], bf16,
// 128 B rows with m97 XOR-8 slot swizzle (conflict-free, verified R2:
// SQ_LDS_BANK_CONFLICT 4.85M -> 131K).
// Staging unit j = rows j*64+wave*8..+7 (1 GLD/wave). Reads: A units 0,2
// last ds_read at P3, units 1,3 at P4; B all units last at P3.
// DEEP schedule (R3): every staged unit gets >=2 phases before tile-end wait:
//   P1: stage B2,B3,A0,A2 (T+1) -> nbuf   [regions dead since T-1.P3]
//   P2: stage A1,A3 (T+1)        -> nbuf  [dead since T-1.P4]
//   P3: no stage
//   P4: stage B0,B1 (T+2)        -> buf   [dead since T.P3]
//   tile end: s_waitcnt vmcnt(2)  (only P4's pair still in flight)
// MODE 0 (qkv): bx<8 -> bf16 to QK; bx>=8 -> LDS-transpose -> Vt.
// MODE 1 (score): bf16 exp(acc*alpha) + row-sum atomicAdd into Lrow.
// ================================================================
template <int MODE>
__device__ __forceinline__ void gemm256_body(
    const unsigned short* __restrict__ A, const unsigned short* __restrict__ B,
    void* __restrict__ Cv, int K, int lda, int ldb, int ldc,
    long sA, long sB, long sC, float alpha, float* __restrict__ Lrow,
    unsigned short* __restrict__ Vt) {
  __shared__ __align__(16) unsigned short smem[65536];  // 128 KiB

  const int t = threadIdx.x;
  const int lane = t & 63;
  const int wave = t >> 6;        // 0..7
  const int quad = lane >> 4;     // 0..3
  const int mrow = lane & 15;     // 0..15
  const int wm = wave >> 2;       // 0..1  (M half)
  const int wn = wave & 3;        // 0..3  (N quarter)

  int bx, by, b;
  xcd_swizzle(bx, by, b);
  const int rowA0 = by * 256;
  const int rowB0 = bx * 256;
  const unsigned short* Ab = A + (long)b * sA;
  const unsigned short* Bb = B + (long)b * sB;

  // staging: lane l -> row (l>>3), global k-slot (l&7)^(l>>3); dest linear
  const int srow = lane >> 3;                 // 0..7
  const int scol = ((lane & 7) ^ srow) * 8;   // pre-swizzled source col (elems)

  // hoisted per-unit global base pointers (unit j = rows j*64+wave*8..+7)
  const unsigned short* gA[4];
  const unsigned short* gB[4];
#pragma unroll
  for (int j = 0; j < 4; ++j) {
    gA[j] = Ab + (long)(rowA0 + j * 64 + wave * 8 + srow) * lda + scol;
    gB[j] = Bb + (long)(rowB0 + j * 64 + wave * 8 + srow) * ldb + scol;
  }
  // LDS dest elem-offset for unit j within a region: j*4096 + wave*512
  const int dst = wave * 512;

  f32x4 acc[8][4];
#pragma unroll
  for (int i = 0; i < 8; ++i)
#pragma unroll
    for (int j = 0; j < 4; ++j) {
      f32x4 z = {0.f, 0.f, 0.f, 0.f};
      acc[i][j] = z;
    }

  const int NT = K >> 6;

  // prologue: T0 fully into buf0; T1.{B0,B1} into buf1 (mimics a T-1.P4)
  {
#pragma unroll
    for (int j = 0; j < 4; ++j) GLD_LDS16(gA[j], smem + j * 4096 + dst);
#pragma unroll
    for (int j = 0; j < 4; ++j)
      GLD_LDS16(gB[j], smem + 16384 + j * 4096 + dst);
    if (NT > 1) {
      GLD_LDS16(gB[0] + 64, smem + 32768 + 16384 + 0 * 4096 + dst);
      GLD_LDS16(gB[1] + 64, smem + 32768 + 16384 + 1 * 4096 + dst);
      asm volatile("s_waitcnt vmcnt(2)" ::: "memory");
    } else {
      asm volatile("s_waitcnt vmcnt(0)" ::: "memory");
    }
    bar();
  }

  const int m7 = mrow & 7;
  const int aslot0 = (quad ^ m7) * 8;  // ks=0 read slot (elems); ks=1: ^32

  for (int T = 0; T < NT; ++T) {
    const int boff = (T & 1) << 15;  // 0 / 32768 elems
    const int noff = boff ^ 32768;
    const unsigned short* As = smem + boff;
    const unsigned short* Bs = smem + boff + 16384;
    const int kt1 = (T + 1) << 6;
    const int kt2 = (T + 2) << 6;
    short8 af[4], bf[4];

    // ---------------- P1: ks=0, m-half 0 | stage B2,B3,A0,A2 (T+1) --------
#pragma unroll
    for (int i = 0; i < 4; ++i)
      af[i] = *(const short8*)(As + (wm * 128 + i * 16 + mrow) * 64 + aslot0);
#pragma unroll
    for (int j = 0; j < 4; ++j)
      bf[j] = *(const short8*)(Bs + (wn * 64 + j * 16 + mrow) * 64 + aslot0);
    if (T + 1 < NT) {
      GLD_LDS16(gB[2] + kt1, smem + noff + 16384 + 2 * 4096 + dst);
      GLD_LDS16(gB[3] + kt1, smem + noff + 16384 + 3 * 4096 + dst);
      GLD_LDS16(gA[0] + kt1, smem + noff + 0 * 4096 + dst);
      GLD_LDS16(gA[2] + kt1, smem + noff + 2 * 4096 + dst);
    }
    bar();
    __builtin_amdgcn_sched_barrier(0);
    __builtin_amdgcn_s_setprio(1);
#pragma unroll
    for (int i = 0; i < 4; ++i)
#pragma unroll
      for (int j = 0; j < 4; ++j)
        acc[i][j] = __builtin_amdgcn_mfma_f32_16x16x32_bf16(af[i], bf[j],
                                                            acc[i][j], 0, 0, 0);
    __builtin_amdgcn_s_setprio(0);
    __builtin_amdgcn_sched_barrier(0);
    bar();

    // ---------------- P2: ks=0, m-half 1 (bf reused) | stage A1,A3 --------
#pragma unroll
    for (int i = 0; i < 4; ++i)
      af[i] =
          *(const short8*)(As + (wm * 128 + 64 + i * 16 + mrow) * 64 + aslot0);
    if (T + 1 < NT) {
      GLD_LDS16(gA[1] + kt1, smem + noff + 1 * 4096 + dst);
      GLD_LDS16(gA[3] + kt1, smem + noff + 3 * 4096 + dst);
    }
    bar();
    __builtin_amdgcn_sched_barrier(0);
    __builtin_amdgcn_s_setprio(1);
#pragma unroll
    for (int i = 0; i < 4; ++i)
#pragma unroll
      for (int j = 0; j < 4; ++j)
        acc[4 + i][j] = __builtin_amdgcn_mfma_f32_16x16x32_bf16(
            af[i], bf[j], acc[4 + i][j], 0, 0, 0);
    __builtin_amdgcn_s_setprio(0);
    __builtin_amdgcn_sched_barrier(0);
    bar();

    // ---------------- P3: ks=1, m-half 0 | no stage ----------------
#pragma unroll
    for (int i = 0; i < 4; ++i)
      af[i] = *(const short8*)(As + (wm * 128 + i * 16 + mrow) * 64 +
                               (aslot0 ^ 32));
#pragma unroll
    for (int j = 0; j < 4; ++j)
      bf[j] = *(const short8*)(Bs + (wn * 64 + j * 16 + mrow) * 64 +
                               (aslot0 ^ 32));
    bar();
    __builtin_amdgcn_sched_barrier(0);
    __builtin_amdgcn_s_setprio(1);
#pragma unroll
    for (int i = 0; i < 4; ++i)
#pragma unroll
      for (int j = 0; j < 4; ++j)
        acc[i][j] = __builtin_amdgcn_mfma_f32_16x16x32_bf16(af[i], bf[j],
                                                            acc[i][j], 0, 0, 0);
    __builtin_amdgcn_s_setprio(0);
    __builtin_amdgcn_sched_barrier(0);
    bar();

    // ---------------- P4: ks=1, m-half 1 (bf reused) | stage B0,B1 (T+2) --
#pragma unroll
    for (int i = 0; i < 4; ++i)
      af[i] = *(const short8*)(As + (wm * 128 + 64 + i * 16 + mrow) * 64 +
                               (aslot0 ^ 32));
    if (T + 2 < NT) {
      GLD_LDS16(gB[0] + kt2, smem + boff + 16384 + 0 * 4096 + dst);
      GLD_LDS16(gB[1] + kt2, smem + boff + 16384 + 1 * 4096 + dst);
    }
    bar();
    __builtin_amdgcn_sched_barrier(0);
    __builtin_amdgcn_s_setprio(1);
#pragma unroll
    for (int i = 0; i < 4; ++i)
#pragma unroll
      for (int j = 0; j < 4; ++j)
        acc[4 + i][j] = __builtin_amdgcn_mfma_f32_16x16x32_bf16(
            af[i], bf[j], acc[4 + i][j], 0, 0, 0);
    __builtin_amdgcn_s_setprio(0);
    __builtin_amdgcn_sched_barrier(0);
    if (T + 2 < NT) {
      asm volatile("s_waitcnt vmcnt(2)" ::: "memory");
    } else {
      asm volatile("s_waitcnt vmcnt(0)" ::: "memory");
    }
    bar();
  }

  // -------------------- epilogue --------------------
  const long cb = (long)b * sC;

  if constexpr (MODE == 0) {
    if (bx < 8) {
      unsigned short* C = (unsigned short*)Cv;
#pragma unroll
      for (int m = 0; m < 8; ++m) {
        int row = rowA0 + wm * 128 + m * 16 + quad * 4;
#pragma unroll
        for (int j = 0; j < 4; ++j) {
          int col = rowB0 + wn * 64 + j * 16 + mrow;
#pragma unroll
          for (int r = 0; r < 4; ++r)
            C[(long)(row + r) * ldc + col] = f2bf(acc[m][j][r]);
        }
      }
    } else {
      // V: transpose via LDS (smem reused as [e 256][s 256] bf16, 128 KiB)
      // swz bits 3-6 only -> 4-aligned ushort4 writes / 8-aligned ushort8 reads
#pragma unroll
      for (int m = 0; m < 8; ++m) {
        int s4 = wm * 128 + m * 16 + quad * 4;
#pragma unroll
        for (int j = 0; j < 4; ++j) {
          int e = wn * 64 + j * 16 + mrow;
          int swz = ((e & 7) << 4) ^ (((e >> 3) & 3) << 3);
          ushort4 pk;
          pk.x = f2bf(acc[m][j][0]);
          pk.y = f2bf(acc[m][j][1]);
          pk.z = f2bf(acc[m][j][2]);
          pk.w = f2bf(acc[m][j][3]);
          *(ushort4*)(smem + e * 256 + (s4 ^ swz)) = pk;
        }
      }
      __syncthreads();
      const int batch = by >> 3;
      const int s_base = (by & 7) * 256;
      const int e_base = (bx - 8) * 256;
      unsigned short* VtB = Vt + (long)batch * 1024 * 2048;
      const int er = t >> 5;          // 0..15
      const int s = (t & 31) * 8;     // 0..248
#pragma unroll
      for (int rnd = 0; rnd < 16; ++rnd) {
        int e = rnd * 16 + er;
        int swz = ((e & 7) << 4) ^ (((e >> 3) & 3) << 3);
        ushort8 v = *(const ushort8*)(smem + e * 256 + (s ^ swz));
        *(ushort8*)(VtB + (long)(e_base + e) * 2048 + s_base + s) = v;
      }
    }
  } else {
    // MODE 1: E = exp(acc*alpha) -> bf16; row sums -> Lrow
    unsigned short* C = (unsigned short*)Cv;
    float p[8][4];
#pragma unroll
    for (int m = 0; m < 8; ++m)
#pragma unroll
      for (int r = 0; r < 4; ++r) p[m][r] = 0.f;
#pragma unroll
    for (int m = 0; m < 8; ++m) {
      int row = rowA0 + wm * 128 + m * 16 + quad * 4;
#pragma unroll
      for (int j = 0; j < 4; ++j) {
        int col = rowB0 + wn * 64 + j * 16 + mrow;
#pragma unroll
        for (int r = 0; r < 4; ++r) {
          float e = __expf(acc[m][j][r] * alpha);
          C[cb + (long)(row + r) * ldc + col] = f2bf(e);
          p[m][r] += e;
        }
      }
    }
#pragma unroll
    for (int off = 1; off < 16; off <<= 1)
#pragma unroll
      for (int m = 0; m < 8; ++m)
#pragma unroll
        for (int r = 0; r < 4; ++r)
          p[m][r] += __shfl_xor(p[m][r], off, 64);
    if (mrow == 0) {
#pragma unroll
      for (int m = 0; m < 8; ++m) {
        int row = rowA0 + wm * 128 + m * 16 + quad * 4;
#pragma unroll
        for (int r = 0; r < 4; ++r)
          atomicAdd(&Lrow[b * 2048 + row + r], p[m][r]);
      }
    }
  }
}

// ---------------------------------------------------------------- m97 body,
// kept for the out GEMM (MODE 2 only: fp32 store of acc/Lrow[row]).
template <int MODE>
__device__ __forceinline__ void gemm_body(
    const unsigned short* __restrict__ A, const unsigned short* __restrict__ B,
    void* __restrict__ Cv, int K, int lda, int ldb, int ldc,
    long sA, long sB, long sC, float alpha, float* __restrict__ Lrow,
    unsigned short* __restrict__ Vt) {
  constexpr int BM = 128, BN = 128, BK = 64;
  __shared__ __align__(16) unsigned short smem[BM * BK + BN * BK];  // 32 KB
  unsigned short* As = smem;
  unsigned short* Bs = smem + BM * BK;

  const int t = threadIdx.x;
  const int lane = t & 63;
  const int wave = t >> 6;
  const int quad = lane >> 4;
  const int mrow = lane & 15;
  const int wm = wave >> 1, wn = wave & 1;

  int bx, by, b;
  xcd_swizzle(bx, by, b);
  const int rowA0 = by * BM;
  const int rowB0 = bx * BN;
  const unsigned short* Ab = A + (long)b * sA;
  const unsigned short* Bb = B + (long)b * sB;

  f32x4 acc[4][4];
#pragma unroll
  for (int i = 0; i < 4; ++i)
#pragma unroll
    for (int j = 0; j < 4; ++j) {
      f32x4 z = {0.f, 0.f, 0.f, 0.f};
      acc[i][j] = z;
    }

  const int rbase = wave * 32 + (lane >> 3);
  const int c2 = lane & 7;

  for (int kt = 0; kt < K; kt += BK) {
#pragma unroll
    for (int j = 0; j < 4; ++j) {
      int r = rbase + j * 8;
      int c = c2 ^ (r & 7);
      GLD_LDS16(Ab + (long)(rowA0 + r) * lda + kt + c * 8, As + (wave * 4 + j) * 512);
      GLD_LDS16(Bb + (long)(rowB0 + r) * ldb + kt + c * 8, Bs + (wave * 4 + j) * 512);
    }
    __syncthreads();
#pragma unroll
    for (int ks = 0; ks < 2; ++ks) {
      short8 af[4], bfr[4];
#pragma unroll
      for (int i = 0; i < 4; ++i) {
        int rA = wm * 64 + i * 16 + mrow;
        int cc = ks * 4 + quad;
        af[i] = *(const short8*)(As + (rA * 8 + (cc ^ (rA & 7))) * 8);
        int rB = wn * 64 + i * 16 + mrow;
        bfr[i] = *(const short8*)(Bs + (rB * 8 + (cc ^ (rB & 7))) * 8);
      }
#pragma unroll
      for (int mt = 0; mt < 4; ++mt)
#pragma unroll
        for (int nt = 0; nt < 4; ++nt)
          acc[mt][nt] = __builtin_amdgcn_mfma_f32_16x16x32_bf16(
              af[mt], bfr[nt], acc[mt][nt], 0, 0, 0);
    }
    __syncthreads();
  }

  const int m_base = rowA0 + wm * 64;
  const int n_base = rowB0 + wn * 64;
  const long cb = (long)b * sC;

  // MODE 2 only instantiated: fp32 out, scaled by 1/Lrow[row]
#pragma unroll
  for (int mt = 0; mt < 4; ++mt)
#pragma unroll
    for (int i = 0; i < 4; ++i) {
      int row = m_base + mt * 16 + quad * 4 + i;
      float inv = 1.0f / Lrow[b * 2048 + row];
#pragma unroll
      for (int nt = 0; nt < 4; ++nt) {
        int col = n_base + nt * 16 + mrow;
        ((float*)Cv)[cb + (long)row * ldc + col] = acc[mt][nt][i] * inv;
      }
    }
}

// distinct names so rocprof separates the three GEMMs
__global__ __launch_bounds__(512, 2) void qkv_gemm_kernel(
    const unsigned short* __restrict__ A, const unsigned short* __restrict__ B,
    void* __restrict__ Cv, int K, int lda, int ldb, int ldc,
    long sA, long sB, long sC, float alpha, float* __restrict__ Lrow,
    unsigned short* __restrict__ Vt) {
  gemm256_body<0>(A, B, Cv, K, lda, ldb, ldc, sA, sB, sC, alpha, Lrow, Vt);
}
__global__ __launch_bounds__(512, 2) void score_gemm_kernel(
    const unsigned short* __restrict__ A, const unsigned short* __restrict__ B,
    void* __restrict__ Cv, int K, int lda, int ldb, int ldc,
    long sA, long sB, long sC, float alpha, float* __restrict__ Lrow,
    unsigned short* __restrict__ Vt) {
  gemm256_body<1>(A, B, Cv, K, lda, ldb, ldc, sA, sB, sC, alpha, Lrow, Vt);
}
__global__ __launch_bounds__(256, 2) void out_gemm_kernel(
    const unsigned short* __restrict__ A, const unsigned short* __restrict__ B,
    void* __restrict__ Cv, int K, int lda, int ldb, int ldc,
    long sA, long sB, long sC, float alpha, float* __restrict__ Lrow,
    unsigned short* __restrict__ Vt) {
  gemm_body<2>(A, B, Cv, K, lda, ldb, ldc, sA, sB, sC, alpha, Lrow, Vt);
}

// ---------------------------------------------------------------- launch
extern "C" void kernel_launch(void* const* d_in, const int* in_sizes, int n_in,
                              void* d_out, int out_size, void* d_ws, size_t ws_size,
                              hipStream_t stream) {
  const float* X = (const float*)d_in[0];  // [4,2048,1024] fp32
  const float* W = (const float*)d_in[1];  // [1024,3072] fp32
  float* out = (float*)d_out;              // [4,2048,1024] fp32

  char* ws = (char*)d_ws;
  unsigned short* Xb  = (unsigned short*)(ws);                 // 8192x1024 bf16   (16 MiB)
  unsigned short* Wtb = (unsigned short*)(ws + 16777216);      // 3072x1024 bf16   ( 6 MiB)
  unsigned short* QK  = (unsigned short*)(ws + 23068672);      // 8192x2048 bf16   (32 MiB)
  unsigned short* Vt  = (unsigned short*)(ws + 56623104);      // 4x1024x2048 bf16 (16 MiB)
  unsigned short* Sb  = (unsigned short*)(ws + 73400320);      // 4x2048x2048 bf16 (32 MiB)
  float* Lrow         = (float*)(ws + 106954752);              // 4x2048 fp32      (32 KiB)

  // 1. prep: cast X, transpose W, zero Lrow
  prep_kernel<<<4865, 256, 0, stream>>>(X, Xb, W, Wtb, Lrow);

  // 2. [Q|K] = Xb @ Wtb^T  (bx<8 -> QK, ldc=2048); V -> Vt transposed (bx>=8)
  qkv_gemm_kernel<<<dim3(12, 32, 1), 512, 0, stream>>>(
      Xb, Wtb, QK, 1024, 1024, 1024, 2048, 0L, 0L, 0L, 1.0f, nullptr, Vt);

  // 3. E = exp(Q @ K^T / 32) per batch [2048 x 2048], K=1024; row sums -> Lrow
  score_gemm_kernel<<<dim3(8, 8, 4), 512, 0, stream>>>(
      QK, QK + 1024, Sb, 1024, 2048, 2048, 2048,
      (long)2048 * 2048, (long)2048 * 2048, (long)2048 * 2048, 0.03125f, Lrow, nullptr);

  // 4. O = (E @ Vt^T) / L  per batch  [2048 x 1024], K=2048 -> fp32 out
  out_gemm_kernel<<<dim3(8, 16, 4), 256, 0, stream>>>(
      Sb, Vt, out, 2048, 2048, 2048, 1024,
      (long)2048 * 2048, (long)1024 * 2048, (long)2048 * 1024, 1.0f, Lrow, nullptr);
}